// Round 7
// baseline (603.999 us; speedup 1.0000x reference)
//
#include <hip/hip_runtime.h>
#include <hip/hip_cooperative_groups.h>

namespace cg = cooperative_groups;

#define HH 2048
#define WW 2048
#define NN (HH*WW)

static constexpr unsigned RANK0 = 1677721u;   // floor(0.4*(NN-1))
static constexpr unsigned KEYLO = 0xB000u;
static constexpr unsigned KEYHI_ = 0xC000u;
static constexpr int NBINS = 4096;
static constexpr int MORPH_BLOCKS = 512;      // 2 tiles per block, 1024 tiles
static constexpr int MEGA_BLOCKS = 1024;      // 4 blocks/CU co-resident (coop)

// fused morph tile geometry: 32x128 tile, halo 6
#define TH 32
#define TW 128
#define LR 44            // TH + 12 rows
#define LCP 148          // padded LDS row stride in floats (data cols [0,144))

struct Scal {
  unsigned keyhiA, keyhiB, rA, rB;
  double thr, c0, c1;
};

// ws layout: [bufA NN floats][zeroed ctl: coarse|under|over|midA|midB|h2A|h2B][scal][part]
static constexpr size_t OFF_CTL    = (size_t)NN * 4;
static constexpr size_t OFF_COARSE = OFF_CTL;
static constexpr size_t OFF_UNDER  = OFF_COARSE + (size_t)NBINS * 4;
static constexpr size_t OFF_OVER   = OFF_UNDER + 4;
static constexpr size_t OFF_MIDA   = OFF_OVER + 4;
static constexpr size_t OFF_MIDB   = OFF_MIDA + 1024;
static constexpr size_t OFF_H2A    = OFF_MIDB + 1024;
static constexpr size_t OFF_H2B    = OFF_H2A + 65536ull * 4;
static constexpr size_t CTL_END    = OFF_H2B + 65536ull * 4;
static constexpr size_t CTL_BYTES  = CTL_END - OFF_CTL;
static constexpr size_t OFF_SCAL   = CTL_END;                // 8-aligned
static constexpr size_t OFF_PART   = OFF_SCAL + 64;

__device__ __forceinline__ float mx3(float a, float b, float c){ return fmaxf(fmaxf(a,b),c); }
__device__ __forceinline__ float mn3(float a, float b, float c){ return fminf(fminf(a,b),c); }

__device__ __forceinline__ unsigned keyf(float x){
  unsigned b = __float_as_uint(x);
  return (b & 0x80000000u) ? ~b : (b | 0x80000000u);
}
__device__ __forceinline__ float keyinv(unsigned k){
  unsigned b = (k & 0x80000000u) ? (k ^ 0x80000000u) : ~k;
  return __uint_as_float(b);
}

// read one LDS row window for col-group g: aligned float4 + neighbors via shuffle;
// wave-boundary / tile-edge lanes patch with a clamped LDS read (clamp garbage
// only touches cols 0/143 which stay outside the pristine ring at every stage).
__device__ __forceinline__ void loadrow(const float* __restrict__ src, int lr, int g, int lane,
                                        float4& v, float& L, float& R){
  v = *reinterpret_cast<const float4*>(&src[lr*LCP + 4*g]);
  L = __shfl_up(v.w, 1);
  R = __shfl_down(v.x, 1);
  if (lane == 0 || g == 0)   L = src[lr*LCP + (g ? 4*g - 1 : 0)];
  if (lane == 63 || g == 35) R = src[lr*LCP + ((g == 35) ? 143 : 4*g + 4)];
}

__device__ __forceinline__ void morph4(bool DIL,
    const float pr[6], const float cr[6], const float nr[6], float w[4]){
  #pragma unroll
  for (int i = 0; i < 4; i++){
    if (DIL){
      float Ah = mx3(cr[i],   cr[i+1], cr[i+2]);
      float Av = mx3(pr[i+1], cr[i+1], nr[i+1]);
      float Ad = mx3(pr[i],   cr[i+1], nr[i+2]);
      float Aa = mx3(pr[i+2], cr[i+1], nr[i]);
      float tm = mx3(pr[i], pr[i+1], pr[i+2]);
      float bm = mx3(nr[i], nr[i+1], nr[i+2]);
      float M9 = mx3(tm, Ah, bm);
      w[i] = fmaxf(M9, 1.0f + fminf(fminf(Ah,Av), fminf(Ad,Aa)));
    } else {
      float Bh = mn3(cr[i],   cr[i+1], cr[i+2]);
      float Bv = mn3(pr[i+1], cr[i+1], nr[i+1]);
      float Bd = mn3(pr[i],   cr[i+1], nr[i+2]);
      float Ba = mn3(pr[i+2], cr[i+1], nr[i]);
      float tm = mn3(pr[i], pr[i+1], pr[i+2]);
      float bm = mn3(nr[i], nr[i+1], nr[i+2]);
      float m9 = mn3(tm, Bh, bm);
      w[i] = fminf(m9, fmaxf(fmaxf(Bh,Bv), fmaxf(Bd,Ba)) - 1.0f);
    }
  }
}

// All 6 smoothing ops (D,E,E,D,D,E) per 32x128 tile in double-buffered LDS.
// Each block handles 2 tiles; tile1's global loads are issued into registers
// BEFORE tile0's compute so HBM latency hides under the LDS phases.
__global__ __launch_bounds__(256)
void fused_morph_k(const float* __restrict__ in, float* __restrict__ out,
                   unsigned* __restrict__ gh, unsigned* __restrict__ under,
                   unsigned* __restrict__ over){
  __shared__ float lds[2][LR*LCP];
  __shared__ unsigned lh[NBINS/2];       // packed u16 bins; <=8192 per bin over 2 tiles
  for (int i = threadIdx.x; i < NBINS/2; i += 256) lh[i] = 0;

  const int t = threadIdx.x;
  const int g = t % 36, s = t / 36;      // strip s computes rows [6s+1, 6s+7)
  const bool active = (t < 252);
  const int lane = t & 63;
  const bool dilf[6] = {true,false,false,true,true,false};

  int tile = blockIdx.x;
  // ---- stage-in tile0: 44 rows x 36 float4 (rows r0-6.., cols c0-8..), zero-padded
  {
    const int r0 = (tile >> 4)*TH, c0 = (tile & 15)*TW;
    for (int idx = t; idx < LR*36; idx += 256){
      int lr = idx / 36, gq = idx % 36;
      int gr = r0 - 6 + lr, gc = c0 - 8 + 4*gq;
      float4 v = make_float4(0.f,0.f,0.f,0.f);
      if ((unsigned)gr < (unsigned)HH && (unsigned)gc < (unsigned)WW)
        v = *reinterpret_cast<const float4*>(in + (size_t)gr*WW + gc);
      *reinterpret_cast<float4*>(&lds[0][lr*LCP + 4*gq]) = v;
    }
  }
  __syncthreads();

  unsigned uc = 0, oc = 0;
  float4 pref[7];

  #pragma unroll 1
  for (int tt = 0; tt < 2; tt++){
    const int r0 = (tile >> 4)*TH, c0 = (tile & 15)*TW;
    if (tt == 0){
      const int tile1 = blockIdx.x + MORPH_BLOCKS;
      const int r1 = (tile1 >> 4)*TH, c1 = (tile1 & 15)*TW;
      #pragma unroll
      for (int j = 0; j < 7; j++){
        int idx = t + j*256;
        float4 v = make_float4(0.f,0.f,0.f,0.f);
        if (idx < LR*36){
          int lr = idx / 36, gq = idx % 36;
          int gr = r1 - 6 + lr, gc = c1 - 8 + 4*gq;
          if ((unsigned)gr < (unsigned)HH && (unsigned)gc < (unsigned)WW)
            v = *reinterpret_cast<const float4*>(in + (size_t)gr*WW + gc);
        }
        pref[j] = v;
      }
    }
    const int gcBase = c0 - 8 + 4*g;

    #pragma unroll 1
    for (int st = 0; st < 6; st++){
      const float* src = lds[st & 1];
      float*       dst = lds[(st & 1) ^ 1];
      if (active){
        const bool DIL = dilf[st];
        float4 vp, vc;  float pL,pR,cL,cR;
        loadrow(src, 6*s,     g, lane, vp, pL, pR);
        loadrow(src, 6*s + 1, g, lane, vc, cL, cR);
        #pragma unroll 1
        for (int k = 0; k < 6; k++){
          int lr = 6*s + 1 + k;
          float4 vn; float nL,nR;
          loadrow(src, lr + 1, g, lane, vn, nL, nR);
          float pr[6] = {pL, vp.x, vp.y, vp.z, vp.w, pR};
          float cr[6] = {cL, vc.x, vc.y, vc.z, vc.w, cR};
          float nr[6] = {nL, vn.x, vn.y, vn.z, vn.w, nR};
          float w[4];
          morph4(DIL, pr, cr, nr, w);
          int gr = r0 - 6 + lr;
          if ((unsigned)gr >= (unsigned)HH){
            w[0]=w[1]=w[2]=w[3]=0.f;
          } else {
            #pragma unroll
            for (int i = 0; i < 4; i++)
              if ((unsigned)(gcBase + i) >= (unsigned)WW) w[i] = 0.f;
          }
          *reinterpret_cast<float4*>(&dst[lr*LCP + 4*g]) = make_float4(w[0],w[1],w[2],w[3]);
          vp = vc; pL = cL; pR = cR;
          vc = vn; cL = nL; cR = nR;
        }
      }
      __syncthreads();
    }

    // epilogue: store + hist of the pristine 32x128 center (final values in lds[0])
    #pragma unroll
    for (int ii = 0; ii < 4; ii++){
      int idx = t + ii*256;
      int row = idx >> 5, gg = idx & 31;
      float4 v = *reinterpret_cast<const float4*>(&lds[0][(row+6)*LCP + 8 + 4*gg]);
      *reinterpret_cast<float4*>(out + (size_t)(r0+row)*WW + c0 + 4*gg) = v;
      float vv[4] = {v.x, v.y, v.z, v.w};
      #pragma unroll
      for (int i = 0; i < 4; i++){
        unsigned key = keyf(vv[i]);
        unsigned hi = key >> 16;
        if (hi >= KEYLO && hi < KEYHI_){
          unsigned bin = hi - KEYLO;
          atomicAdd(&lh[bin >> 1], 1u << ((bin & 1) << 4));
        }
        else if (hi < KEYLO) uc++;
        else                 oc++;
      }
    }

    if (tt == 0){
      __syncthreads();
      #pragma unroll
      for (int j = 0; j < 7; j++){
        int idx = t + j*256;
        if (idx < LR*36){
          int lr = idx / 36, gq = idx % 36;
          *reinterpret_cast<float4*>(&lds[0][lr*LCP + 4*gq]) = pref[j];
        }
      }
      __syncthreads();
      tile += MORPH_BLOCKS;
    }
  }

  __syncthreads();
  for (int i = threadIdx.x; i < NBINS/2; i += 256){
    unsigned w = lh[i];
    if (w & 0xFFFFu) atomicAdd(&gh[2*i],   w & 0xFFFFu);
    if (w >> 16)     atomicAdd(&gh[2*i+1], w >> 16);
  }
  if (uc) atomicAdd(under, uc);
  if (oc) atomicAdd(over, oc);
}

// 6-col window of global row via 1 float4 + shuffles (scalar patch on lanes 0/63)
__device__ __forceinline__ void growin(const float* __restrict__ p, int row, int q, int lane,
                                       float w[6]){
  if ((unsigned)row >= (unsigned)HH){
    w[0]=w[1]=w[2]=w[3]=w[4]=w[5]=0.f;
    return;
  }
  const float* rp = p + (size_t)row * WW;
  float4 v = *reinterpret_cast<const float4*>(rp + 4*q);
  float L = __shfl_up(v.w, 1);
  float R = __shfl_down(v.x, 1);
  if (q == 0)            L = 0.f;
  else if (lane == 0)    L = rp[4*q - 1];
  if (q == 511)          R = 0.f;
  else if (lane == 63)   R = rp[4*q + 4];
  w[0]=L; w[1]=v.x; w[2]=v.y; w[3]=v.z; w[4]=v.w; w[5]=R;
}

// Everything post-morph in ONE cooperative kernel:
// P0 b0: coarse scan  | P1: mid-hist + (mid,low) 2D hist | P2 b0: mid+low scan -> thr
// P3: balloon + f64 partials | P4 b0: c0/c1 | P5: final CV write
__global__ __launch_bounds__(256, 4)
void mega_k(float* xio, const float* __restrict__ orig, float* __restrict__ xb,
            const unsigned* __restrict__ coarse, const unsigned* __restrict__ under,
            Scal* sc, unsigned* __restrict__ midA, unsigned* __restrict__ midB,
            unsigned* __restrict__ h2A, unsigned* __restrict__ h2B,
            double* __restrict__ part){
  cg::grid_group grid = cg::this_grid();
  const int t = threadIdx.x;
  __shared__ unsigned shA[256], shB[256], shEx[256];
  __shared__ unsigned shRes[8];
  __shared__ double shD[4][3];

  // ---------------- P0: coarse scan (block 0) ----------------
  if (blockIdx.x == 0){
    unsigned loc = 0;
    #pragma unroll
    for (int i = 0; i < NBINS/256; i++) loc += coarse[t*(NBINS/256) + i];
    shA[t] = loc;
    __syncthreads();
    if (t == 0){
      unsigned run = under[0];
      for (int i = 0; i < 256; i++){ shEx[i] = run; run += shA[i]; }
    }
    __syncthreads();
    unsigned run = shEx[t];
    const unsigned r0 = RANK0, r1 = RANK0 + 1;
    #pragma unroll
    for (int i = 0; i < NBINS/256; i++){
      unsigned idx = t*(NBINS/256) + i;
      unsigned cc = coarse[idx];
      if (cc){
        if (r0 >= run && r0 - run < cc){ sc->keyhiA = KEYLO + idx; sc->rA = r0 - run; }
        if (r1 >= run && r1 - run < cc){ sc->keyhiB = KEYLO + idx; sc->rB = r1 - run; }
      }
      run += cc;
    }
    __threadfence();
  }
  grid.sync();

  // ---------------- P1: fine pass (mid hist + 2D hist) ----------------
  {
    unsigned ha = sc->keyhiA, hb = sc->keyhiB;
    bool dup = (ha == hb);
    shA[t] = 0; shB[t] = 0;
    __syncthreads();
    const int nItems = NN/4;
    const int stride = gridDim.x * blockDim.x;
    for (int it = blockIdx.x*blockDim.x + t; it < nItems; it += stride){
      float4 v = reinterpret_cast<const float4*>(xio)[it];
      float vv[4] = {v.x, v.y, v.z, v.w};
      #pragma unroll
      for (int j = 0; j < 4; j++){
        unsigned key = keyf(vv[j]);
        unsigned hi = key >> 16;
        if (hi == ha){ atomicAdd(&shA[(key>>8)&255], 1u); atomicAdd(&h2A[key & 0xFFFFu], 1u); }
        else if (hi == hb){ atomicAdd(&shB[(key>>8)&255], 1u); atomicAdd(&h2B[key & 0xFFFFu], 1u); }
      }
    }
    __syncthreads();
    if (shA[t]) atomicAdd(&midA[t], shA[t]);
    if (!dup && shB[t]) atomicAdd(&midB[t], shB[t]);
  }
  grid.sync();

  // ---------------- P2: mid + low scans -> thr (block 0) ----------------
  if (blockIdx.x == 0){
    unsigned ha = sc->keyhiA, hb = sc->keyhiB;
    bool dupHi = (ha == hb);
    unsigned rA = sc->rA, rB = sc->rB;
    // mid A (and B if same hi bin)
    shA[t] = midA[t];
    __syncthreads();
    if (t == 0){ unsigned run = 0; for (int i = 0; i < 256; i++){ shEx[i] = run; run += shA[i]; } }
    __syncthreads();
    if (rA >= shEx[t] && rA - shEx[t] < shA[t]){ shRes[0] = (unsigned)t; shRes[1] = rA - shEx[t]; }
    if (dupHi && rB >= shEx[t] && rB - shEx[t] < shA[t]){ shRes[2] = (unsigned)t; shRes[3] = rB - shEx[t]; }
    __syncthreads();
    if (!dupHi){
      shA[t] = midB[t];
      __syncthreads();
      if (t == 0){ unsigned run = 0; for (int i = 0; i < 256; i++){ shEx[i] = run; run += shA[i]; } }
      __syncthreads();
      if (rB >= shEx[t] && rB - shEx[t] < shA[t]){ shRes[2] = (unsigned)t; shRes[3] = rB - shEx[t]; }
      __syncthreads();
    }
    unsigned mA = shRes[0], rA2 = shRes[1], mB = shRes[2], rB2 = shRes[3];
    bool dupMid = dupHi && (mA == mB);
    // low A from h2A row mA
    shA[t] = h2A[mA*256 + t];
    __syncthreads();
    if (t == 0){ unsigned run = 0; for (int i = 0; i < 256; i++){ shEx[i] = run; run += shA[i]; } }
    __syncthreads();
    if (rA2 >= shEx[t] && rA2 - shEx[t] < shA[t]) shRes[4] = (unsigned)t;
    if (dupMid && rB2 >= shEx[t] && rB2 - shEx[t] < shA[t]) shRes[5] = (unsigned)t;
    __syncthreads();
    if (!dupMid){
      const unsigned* srcH = dupHi ? h2A : h2B;
      shA[t] = srcH[mB*256 + t];
      __syncthreads();
      if (t == 0){ unsigned run = 0; for (int i = 0; i < 256; i++){ shEx[i] = run; run += shA[i]; } }
      __syncthreads();
      if (rB2 >= shEx[t] && rB2 - shEx[t] < shA[t]) shRes[5] = (unsigned)t;
      __syncthreads();
    }
    if (t == 0){
      unsigned ka = (ha << 16) | (mA << 8) | shRes[4];
      unsigned kb = (hb << 16) | (mB << 8) | shRes[5];
      double va = (double)keyinv(ka), vb = (double)keyinv(kb);
      const double FRAC = 0.4*(double)(NN-1) - (double)RANK0;   // np's gamma
      sc->thr = va + (vb - va) * FRAC;
      __threadfence();
    }
  }
  grid.sync();

  // ---------------- P3: balloon + f64 partial sums ----------------
  {
    double thr = sc->thr;
    double s0 = 0.0, s1 = 0.0, s2 = 0.0;   // So, Sx, Sox
    const int nItems = NN/4;
    const int stride = gridDim.x * blockDim.x;
    const int lane = t & 63;
    for (int it = blockIdx.x*blockDim.x + t; it < nItems; it += stride){
      int i = it >> 9;
      int q = it & 511;
      float a[6], b[6], c[6];
      growin(xio, i-1, q, lane, a);
      growin(xio, i,   q, lane, b);
      growin(xio, i+1, q, lane, c);
      float4 og = *reinterpret_cast<const float4*>(orig + (size_t)i*WW + 4*q);
      float ov[4] = {og.x, og.y, og.z, og.w};
      float r[4];
      #pragma unroll
      for (int j = 0; j < 4; j++){
        float M9 = mx3(mx3(a[j],a[j+1],a[j+2]), mx3(b[j],b[j+1],b[j+2]), mx3(c[j],c[j+1],c[j+2]));
        float aux = 1.0f + M9;
        float nx = ((double)ov[j] > thr) ? aux : b[j+1];
        r[j] = nx;
        s0 += (double)ov[j];
        s1 += (double)nx;
        s2 += (double)ov[j] * (double)nx;
      }
      *reinterpret_cast<float4*>(xb + (size_t)i*WW + 4*q) = make_float4(r[0],r[1],r[2],r[3]);
    }
    for (int off = 32; off > 0; off >>= 1){
      s0 += __shfl_down(s0, off);
      s1 += __shfl_down(s1, off);
      s2 += __shfl_down(s2, off);
    }
    int wv = t >> 6;
    if ((t & 63) == 0){ shD[wv][0] = s0; shD[wv][1] = s1; shD[wv][2] = s2; }
    __syncthreads();
    if (t == 0){
      part[blockIdx.x*3+0] = shD[0][0]+shD[1][0]+shD[2][0]+shD[3][0];
      part[blockIdx.x*3+1] = shD[0][1]+shD[1][1]+shD[2][1]+shD[3][1];
      part[blockIdx.x*3+2] = shD[0][2]+shD[1][2]+shD[2][2]+shD[3][2];
    }
  }
  grid.sync();

  // ---------------- P4: c0/c1 (block 0) ----------------
  if (blockIdx.x == 0){
    double s0 = 0, s1 = 0, s2 = 0;
    for (int b = t; b < MEGA_BLOCKS; b += 256){
      s0 += part[b*3+0]; s1 += part[b*3+1]; s2 += part[b*3+2];
    }
    for (int off = 32; off > 0; off >>= 1){
      s0 += __shfl_down(s0, off);
      s1 += __shfl_down(s1, off);
      s2 += __shfl_down(s2, off);
    }
    int wv = t >> 6;
    if ((t & 63) == 0){ shD[wv][0] = s0; shD[wv][1] = s1; shD[wv][2] = s2; }
    __syncthreads();
    if (t == 0){
      double So = shD[0][0]+shD[1][0]+shD[2][0]+shD[3][0];
      double Sx = shD[0][1]+shD[1][1]+shD[2][1]+shD[3][1];
      double Sox= shD[0][2]+shD[1][2]+shD[2][2]+shD[3][2];
      sc->c0 = (So - Sox) / ((double)NN - Sx + 1e-8);
      sc->c1 = Sox / (Sx + 1e-8);
      __threadfence();
    }
  }
  grid.sync();

  // ---------------- P5: final Chan-Vese write ----------------
  {
    double c0 = sc->c0, c1 = sc->c1;
    const int nItems = NN/4;
    const int stride = gridDim.x * blockDim.x;
    for (int it = blockIdx.x*blockDim.x + t; it < nItems; it += stride){
      float4 og = reinterpret_cast<const float4*>(orig)[it];
      float4 xv = reinterpret_cast<const float4*>(xb)[it];
      float ov[4] = {og.x, og.y, og.z, og.w};
      float xx[4] = {xv.x, xv.y, xv.z, xv.w};
      float r[4];
      #pragma unroll
      for (int j = 0; j < 4; j++){
        double o = (double)ov[j];
        double d1 = o - c1, d0 = o - c0;
        double cv = d1*d1 - d0*d0;
        r[j] = (cv < 0.0) ? 1.0f : ((cv > 0.0) ? 0.0f : xx[j]);
      }
      reinterpret_cast<float4*>(xio)[it] = make_float4(r[0],r[1],r[2],r[3]);
    }
  }
}

extern "C" void kernel_launch(void* const* d_in, const int* in_sizes, int n_in,
                              void* d_out, int out_size, void* d_ws, size_t ws_size,
                              hipStream_t stream) {
  const float* input  = (const float*)d_in[0];
  const float* origin = (const float*)d_in[1];
  float* out = (float*)d_out;

  char* ws = (char*)d_ws;
  float*    bufA   = (float*)ws;
  unsigned* coarse = (unsigned*)(ws + OFF_COARSE);
  unsigned* under  = (unsigned*)(ws + OFF_UNDER);
  unsigned* over   = (unsigned*)(ws + OFF_OVER);
  unsigned* midA   = (unsigned*)(ws + OFF_MIDA);
  unsigned* midB   = (unsigned*)(ws + OFF_MIDB);
  unsigned* h2A    = (unsigned*)(ws + OFF_H2A);
  unsigned* h2B    = (unsigned*)(ws + OFF_H2B);
  Scal*     scal   = (Scal*)(ws + OFF_SCAL);
  double*   part   = (double*)(ws + OFF_PART);

  hipMemsetAsync(ws + OFF_CTL, 0, CTL_BYTES, stream);

  // all 6 smoothing ops + coarse hist; 2 tiles/block with register prefetch
  fused_morph_k<<<MORPH_BLOCKS, 256, 0, stream>>>(input, out, coarse, under, over);

  // everything else in one cooperative kernel
  float* xio = out;
  const float* orig_p = origin;
  float* xb = bufA;
  const unsigned* coarse_p = coarse;
  const unsigned* under_p = under;
  void* args[] = { &xio, &orig_p, &xb, &coarse_p, &under_p,
                   &scal, &midA, &midB, &h2A, &h2B, &part };
  hipLaunchCooperativeKernel((const void*)mega_k, dim3(MEGA_BLOCKS), dim3(256),
                             args, 0, stream);
  (void)over; (void)in_sizes; (void)n_in; (void)out_size; (void)ws_size;
}

// Round 8
// 142.843 us; speedup vs baseline: 4.2284x; 4.2284x over previous
//
#include <hip/hip_runtime.h>

#define HH 2048
#define WW 2048
#define NN (HH*WW)

static constexpr unsigned RANK0 = 1677721u;   // floor(0.4*(NN-1))
static constexpr unsigned KEYLO = 0xB000u;
static constexpr unsigned KEYHI_ = 0xC000u;
static constexpr int NBINS = 4096;
static constexpr int NPART = 2048;
static constexpr int MORPH_BLOCKS = 512;      // 2 tiles per block, 1024 tiles

// fused morph tile geometry: 32x128 tile, halo 6
#define TH 32
#define TW 128
#define LR 44            // TH + 12 rows
#define LCP 148          // padded LDS row stride in floats (data cols [0,144))

struct Scal {
  unsigned keyhiA, keyhiB, rA, rB;
  double thr, c0, c1;
};

// ws layout: [bufA NN floats][zeroed ctl: coarse|under|over|midA|midB|h2A|h2B][scal][part]
static constexpr size_t OFF_CTL    = (size_t)NN * 4;
static constexpr size_t OFF_COARSE = OFF_CTL;
static constexpr size_t OFF_UNDER  = OFF_COARSE + (size_t)NBINS * 4;
static constexpr size_t OFF_OVER   = OFF_UNDER + 4;
static constexpr size_t OFF_MIDA   = OFF_OVER + 4;
static constexpr size_t OFF_MIDB   = OFF_MIDA + 1024;
static constexpr size_t OFF_H2A    = OFF_MIDB + 1024;
static constexpr size_t OFF_H2B    = OFF_H2A + 65536ull * 4;
static constexpr size_t CTL_END    = OFF_H2B + 65536ull * 4;
static constexpr size_t CTL_BYTES  = CTL_END - OFF_CTL;
static constexpr size_t OFF_SCAL   = CTL_END;                // 8-aligned
static constexpr size_t OFF_PART   = OFF_SCAL + 64;

__device__ __forceinline__ float mx3(float a, float b, float c){ return fmaxf(fmaxf(a,b),c); }
__device__ __forceinline__ float mn3(float a, float b, float c){ return fminf(fminf(a,b),c); }

__device__ __forceinline__ unsigned keyf(float x){
  unsigned b = __float_as_uint(x);
  return (b & 0x80000000u) ? ~b : (b | 0x80000000u);
}
__device__ __forceinline__ float keyinv(unsigned k){
  unsigned b = (k & 0x80000000u) ? (k ^ 0x80000000u) : ~k;
  return __uint_as_float(b);
}

// read one LDS row window for col-group g: aligned float4 + neighbors via shuffle;
// wave-boundary / tile-edge lanes patch with a clamped LDS read (clamp garbage
// only touches cols 0/143 which stay outside the pristine ring at every stage).
__device__ __forceinline__ void loadrow(const float* __restrict__ src, int lr, int g, int lane,
                                        float4& v, float& L, float& R){
  v = *reinterpret_cast<const float4*>(&src[lr*LCP + 4*g]);
  L = __shfl_up(v.w, 1);
  R = __shfl_down(v.x, 1);
  if (lane == 0 || g == 0)   L = src[lr*LCP + (g ? 4*g - 1 : 0)];
  if (lane == 63 || g == 35) R = src[lr*LCP + ((g == 35) ? 143 : 4*g + 4)];
}

__device__ __forceinline__ void morph4(bool DIL,
    const float pr[6], const float cr[6], const float nr[6], float w[4]){
  #pragma unroll
  for (int i = 0; i < 4; i++){
    if (DIL){
      float Ah = mx3(cr[i],   cr[i+1], cr[i+2]);
      float Av = mx3(pr[i+1], cr[i+1], nr[i+1]);
      float Ad = mx3(pr[i],   cr[i+1], nr[i+2]);
      float Aa = mx3(pr[i+2], cr[i+1], nr[i]);
      float tm = mx3(pr[i], pr[i+1], pr[i+2]);
      float bm = mx3(nr[i], nr[i+1], nr[i+2]);
      float M9 = mx3(tm, Ah, bm);
      w[i] = fmaxf(M9, 1.0f + fminf(fminf(Ah,Av), fminf(Ad,Aa)));
    } else {
      float Bh = mn3(cr[i],   cr[i+1], cr[i+2]);
      float Bv = mn3(pr[i+1], cr[i+1], nr[i+1]);
      float Bd = mn3(pr[i],   cr[i+1], nr[i+2]);
      float Ba = mn3(pr[i+2], cr[i+1], nr[i]);
      float tm = mn3(pr[i], pr[i+1], pr[i+2]);
      float bm = mn3(nr[i], nr[i+1], nr[i+2]);
      float m9 = mn3(tm, Bh, bm);
      w[i] = fminf(m9, fmaxf(fmaxf(Bh,Bv), fmaxf(Bd,Ba)) - 1.0f);
    }
  }
}

// All 6 smoothing ops (D,E,E,D,D,E) per 32x128 tile in double-buffered LDS.
// Each block handles 2 tiles; tile1's global loads are issued into registers
// BEFORE tile0's compute so HBM latency hides under the LDS phases.
__global__ __launch_bounds__(256)
void fused_morph_k(const float* __restrict__ in, float* __restrict__ out,
                   unsigned* __restrict__ gh, unsigned* __restrict__ under,
                   unsigned* __restrict__ over){
  __shared__ float lds[2][LR*LCP];
  __shared__ unsigned lh[NBINS/2];       // packed u16 bins; <=8192 per bin over 2 tiles
  for (int i = threadIdx.x; i < NBINS/2; i += 256) lh[i] = 0;

  const int t = threadIdx.x;
  const int g = t % 36, s = t / 36;      // strip s computes rows [6s+1, 6s+7)
  const bool active = (t < 252);
  const int lane = t & 63;
  const bool dilf[6] = {true,false,false,true,true,false};

  int tile = blockIdx.x;
  {
    const int r0 = (tile >> 4)*TH, c0 = (tile & 15)*TW;
    for (int idx = t; idx < LR*36; idx += 256){
      int lr = idx / 36, gq = idx % 36;
      int gr = r0 - 6 + lr, gc = c0 - 8 + 4*gq;
      float4 v = make_float4(0.f,0.f,0.f,0.f);
      if ((unsigned)gr < (unsigned)HH && (unsigned)gc < (unsigned)WW)
        v = *reinterpret_cast<const float4*>(in + (size_t)gr*WW + gc);
      *reinterpret_cast<float4*>(&lds[0][lr*LCP + 4*gq]) = v;
    }
  }
  __syncthreads();

  unsigned uc = 0, oc = 0;
  float4 pref[7];

  #pragma unroll 1
  for (int tt = 0; tt < 2; tt++){
    const int r0 = (tile >> 4)*TH, c0 = (tile & 15)*TW;
    if (tt == 0){
      const int tile1 = blockIdx.x + MORPH_BLOCKS;
      const int r1 = (tile1 >> 4)*TH, c1 = (tile1 & 15)*TW;
      #pragma unroll
      for (int j = 0; j < 7; j++){
        int idx = t + j*256;
        float4 v = make_float4(0.f,0.f,0.f,0.f);
        if (idx < LR*36){
          int lr = idx / 36, gq = idx % 36;
          int gr = r1 - 6 + lr, gc = c1 - 8 + 4*gq;
          if ((unsigned)gr < (unsigned)HH && (unsigned)gc < (unsigned)WW)
            v = *reinterpret_cast<const float4*>(in + (size_t)gr*WW + gc);
        }
        pref[j] = v;
      }
    }
    const int gcBase = c0 - 8 + 4*g;

    #pragma unroll 1
    for (int st = 0; st < 6; st++){
      const float* src = lds[st & 1];
      float*       dst = lds[(st & 1) ^ 1];
      if (active){
        const bool DIL = dilf[st];
        float4 vp, vc;  float pL,pR,cL,cR;
        loadrow(src, 6*s,     g, lane, vp, pL, pR);
        loadrow(src, 6*s + 1, g, lane, vc, cL, cR);
        #pragma unroll 1
        for (int k = 0; k < 6; k++){
          int lr = 6*s + 1 + k;
          float4 vn; float nL,nR;
          loadrow(src, lr + 1, g, lane, vn, nL, nR);
          float pr[6] = {pL, vp.x, vp.y, vp.z, vp.w, pR};
          float cr[6] = {cL, vc.x, vc.y, vc.z, vc.w, cR};
          float nr[6] = {nL, vn.x, vn.y, vn.z, vn.w, nR};
          float w[4];
          morph4(DIL, pr, cr, nr, w);
          int gr = r0 - 6 + lr;
          if ((unsigned)gr >= (unsigned)HH){
            w[0]=w[1]=w[2]=w[3]=0.f;
          } else {
            #pragma unroll
            for (int i = 0; i < 4; i++)
              if ((unsigned)(gcBase + i) >= (unsigned)WW) w[i] = 0.f;
          }
          *reinterpret_cast<float4*>(&dst[lr*LCP + 4*g]) = make_float4(w[0],w[1],w[2],w[3]);
          vp = vc; pL = cL; pR = cR;
          vc = vn; cL = nL; cR = nR;
        }
      }
      __syncthreads();
    }

    // epilogue: store + hist of the pristine 32x128 center (final values in lds[0])
    #pragma unroll
    for (int ii = 0; ii < 4; ii++){
      int idx = t + ii*256;
      int row = idx >> 5, gg = idx & 31;
      float4 v = *reinterpret_cast<const float4*>(&lds[0][(row+6)*LCP + 8 + 4*gg]);
      *reinterpret_cast<float4*>(out + (size_t)(r0+row)*WW + c0 + 4*gg) = v;
      float vv[4] = {v.x, v.y, v.z, v.w};
      #pragma unroll
      for (int i = 0; i < 4; i++){
        unsigned key = keyf(vv[i]);
        unsigned hi = key >> 16;
        if (hi >= KEYLO && hi < KEYHI_){
          unsigned bin = hi - KEYLO;
          atomicAdd(&lh[bin >> 1], 1u << ((bin & 1) << 4));
        }
        else if (hi < KEYLO) uc++;
        else                 oc++;
      }
    }

    if (tt == 0){
      __syncthreads();
      #pragma unroll
      for (int j = 0; j < 7; j++){
        int idx = t + j*256;
        if (idx < LR*36){
          int lr = idx / 36, gq = idx % 36;
          *reinterpret_cast<float4*>(&lds[0][lr*LCP + 4*gq]) = pref[j];
        }
      }
      __syncthreads();
      tile += MORPH_BLOCKS;
    }
  }

  __syncthreads();
  for (int i = threadIdx.x; i < NBINS/2; i += 256){
    unsigned w = lh[i];
    if (w & 0xFFFFu) atomicAdd(&gh[2*i],   w & 0xFFFFu);
    if (w >> 16)     atomicAdd(&gh[2*i+1], w >> 16);
  }
  if (uc) atomicAdd(under, uc);
  if (oc) atomicAdd(over, oc);
}

__global__ void scan_coarse_k(const unsigned* __restrict__ gh, const unsigned* __restrict__ under,
                              Scal* __restrict__ sc){
  __shared__ unsigned part[256];
  __shared__ unsigned excl[256];
  int t = threadIdx.x;
  unsigned loc = 0;
  #pragma unroll
  for (int i = 0; i < NBINS/256; i++) loc += gh[t*(NBINS/256) + i];
  part[t] = loc;
  __syncthreads();
  if (t == 0){
    unsigned run = under[0];
    for (int i = 0; i < 256; i++){ excl[i] = run; run += part[i]; }
  }
  __syncthreads();
  unsigned run = excl[t];
  const unsigned r0 = RANK0, r1 = RANK0 + 1;
  #pragma unroll
  for (int i = 0; i < NBINS/256; i++){
    unsigned idx = t*(NBINS/256) + i;
    unsigned cc = gh[idx];
    if (cc){
      if (r0 >= run && r0 - run < cc){ sc->keyhiA = KEYLO + idx; sc->rA = r0 - run; }
      if (r1 >= run && r1 - run < cc){ sc->keyhiB = KEYLO + idx; sc->rB = r1 - run; }
    }
    run += cc;
  }
}

// ONE fine pass: 256-bin mid hist (LDS) + speculative 65536-bin (mid,low) 2D hist
__global__ __launch_bounds__(256)
void fine2d_k(const float* __restrict__ x, const Scal* __restrict__ sc,
              unsigned* __restrict__ midA, unsigned* __restrict__ midB,
              unsigned* __restrict__ h2A, unsigned* __restrict__ h2B){
  __shared__ unsigned hA[256], hB[256];
  hA[threadIdx.x] = 0; hB[threadIdx.x] = 0;
  __syncthreads();
  unsigned ha = sc->keyhiA, hb = sc->keyhiB;
  bool dup = (ha == hb);
  const int nItems = NN/4;
  for (int it = blockIdx.x*blockDim.x + threadIdx.x; it < nItems; it += gridDim.x*blockDim.x){
    float4 v = reinterpret_cast<const float4*>(x)[it];
    float vv[4] = {v.x, v.y, v.z, v.w};
    #pragma unroll
    for (int j = 0; j < 4; j++){
      unsigned key = keyf(vv[j]);
      unsigned hi = key >> 16;
      if (hi == ha){ atomicAdd(&hA[(key>>8)&255], 1u); atomicAdd(&h2A[key & 0xFFFFu], 1u); }
      else if (hi == hb){ atomicAdd(&hB[(key>>8)&255], 1u); atomicAdd(&h2B[key & 0xFFFFu], 1u); }
    }
  }
  __syncthreads();
  if (hA[threadIdx.x]) atomicAdd(&midA[threadIdx.x], hA[threadIdx.x]);
  if (!dup && hB[threadIdx.x]) atomicAdd(&midB[threadIdx.x], hB[threadIdx.x]);
}

// resolve mid byte (from midA/midB) then low byte (from the matching h2 row) -> thr
__global__ void scan_ml_k(const unsigned* __restrict__ midA, const unsigned* __restrict__ midB,
                          const unsigned* __restrict__ h2A, const unsigned* __restrict__ h2B,
                          Scal* __restrict__ sc){
  __shared__ unsigned h[256], excl[256];
  __shared__ unsigned res[6];   // mA, rA2, mB, rB2, lowA, lowB
  int t = threadIdx.x;
  unsigned ha = sc->keyhiA, hb = sc->keyhiB;
  bool dupHi = (ha == hb);
  unsigned rA = sc->rA, rB = sc->rB;

  h[t] = midA[t];
  __syncthreads();
  if (t == 0){ unsigned run = 0; for (int i = 0; i < 256; i++){ excl[i] = run; run += h[i]; } }
  __syncthreads();
  if (rA >= excl[t] && rA - excl[t] < h[t]){ res[0] = (unsigned)t; res[1] = rA - excl[t]; }
  if (dupHi && rB >= excl[t] && rB - excl[t] < h[t]){ res[2] = (unsigned)t; res[3] = rB - excl[t]; }
  __syncthreads();
  if (!dupHi){
    h[t] = midB[t];
    __syncthreads();
    if (t == 0){ unsigned run = 0; for (int i = 0; i < 256; i++){ excl[i] = run; run += h[i]; } }
    __syncthreads();
    if (rB >= excl[t] && rB - excl[t] < h[t]){ res[2] = (unsigned)t; res[3] = rB - excl[t]; }
    __syncthreads();
  }
  unsigned mA = res[0], rA2 = res[1], mB = res[2], rB2 = res[3];
  bool dupMid = dupHi && (mA == mB);

  h[t] = h2A[mA*256 + t];
  __syncthreads();
  if (t == 0){ unsigned run = 0; for (int i = 0; i < 256; i++){ excl[i] = run; run += h[i]; } }
  __syncthreads();
  if (rA2 >= excl[t] && rA2 - excl[t] < h[t]) res[4] = (unsigned)t;
  if (dupMid && rB2 >= excl[t] && rB2 - excl[t] < h[t]) res[5] = (unsigned)t;
  __syncthreads();
  if (!dupMid){
    const unsigned* srcH = dupHi ? h2A : h2B;
    h[t] = srcH[mB*256 + t];
    __syncthreads();
    if (t == 0){ unsigned run = 0; for (int i = 0; i < 256; i++){ excl[i] = run; run += h[i]; } }
    __syncthreads();
    if (rB2 >= excl[t] && rB2 - excl[t] < h[t]) res[5] = (unsigned)t;
    __syncthreads();
  }
  if (t == 0){
    unsigned ka = (ha << 16) | (mA << 8) | res[4];
    unsigned kb = (hb << 16) | (mB << 8) | res[5];
    double va = (double)keyinv(ka), vb = (double)keyinv(kb);
    const double FRAC = 0.4*(double)(NN-1) - (double)RANK0;   // np's gamma
    sc->thr = va + (vb - va) * FRAC;
  }
}

// 6-col window of global row via 1 float4 + shuffles (scalar patch on lanes 0/63)
__device__ __forceinline__ void growin(const float* __restrict__ p, int row, int q, int lane,
                                       float w[6]){
  if ((unsigned)row >= (unsigned)HH){
    w[0]=w[1]=w[2]=w[3]=w[4]=w[5]=0.f;
    return;
  }
  const float* rp = p + (size_t)row * WW;
  float4 v = *reinterpret_cast<const float4*>(rp + 4*q);
  float L = __shfl_up(v.w, 1);
  float R = __shfl_down(v.x, 1);
  if (q == 0)            L = 0.f;
  else if (lane == 0)    L = rp[4*q - 1];
  if (q == 511)          R = 0.f;
  else if (lane == 63)   R = rp[4*q + 4];
  w[0]=L; w[1]=v.x; w[2]=v.y; w[3]=v.z; w[4]=v.w; w[5]=R;
}

// balloon result computed ON THE FLY (no store): f64 partial sums of origin, nx, origin*nx
__global__ __launch_bounds__(256)
void sums_k(const float* __restrict__ x, const float* __restrict__ orig,
            const Scal* __restrict__ sc, double* __restrict__ part){
  double thr = sc->thr;
  double s0 = 0.0, s1 = 0.0, s2 = 0.0;
  const int nItems = NN/4;
  const int lane = threadIdx.x & 63;
  for (int it = blockIdx.x*blockDim.x + threadIdx.x; it < nItems; it += gridDim.x*blockDim.x){
    int i = it >> 9;
    int q = it & 511;
    float a[6], b[6], c[6];
    growin(x, i-1, q, lane, a);
    growin(x, i,   q, lane, b);
    growin(x, i+1, q, lane, c);
    float4 og = *reinterpret_cast<const float4*>(orig + (size_t)i*WW + 4*q);
    float ov[4] = {og.x, og.y, og.z, og.w};
    #pragma unroll
    for (int j = 0; j < 4; j++){
      float M9 = mx3(mx3(a[j],a[j+1],a[j+2]), mx3(b[j],b[j+1],b[j+2]), mx3(c[j],c[j+1],c[j+2]));
      float nx = ((double)ov[j] > thr) ? (1.0f + M9) : b[j+1];
      s0 += (double)ov[j];
      s1 += (double)nx;
      s2 += (double)ov[j] * (double)nx;
    }
  }
  for (int off = 32; off > 0; off >>= 1){
    s0 += __shfl_down(s0, off);
    s1 += __shfl_down(s1, off);
    s2 += __shfl_down(s2, off);
  }
  __shared__ double red[4][3];
  int wv = threadIdx.x >> 6;
  if (lane == 0){ red[wv][0] = s0; red[wv][1] = s1; red[wv][2] = s2; }
  __syncthreads();
  if (threadIdx.x == 0){
    part[blockIdx.x*3+0] = red[0][0]+red[1][0]+red[2][0]+red[3][0];
    part[blockIdx.x*3+1] = red[0][1]+red[1][1]+red[2][1]+red[3][1];
    part[blockIdx.x*3+2] = red[0][2]+red[1][2]+red[2][2]+red[3][2];
  }
}

__global__ void c0c1_k(const double* __restrict__ part, Scal* __restrict__ sc){
  int t = threadIdx.x;
  double s0 = 0, s1 = 0, s2 = 0;
  for (int b = t; b < NPART; b += 256){
    s0 += part[b*3+0]; s1 += part[b*3+1]; s2 += part[b*3+2];
  }
  for (int off = 32; off > 0; off >>= 1){
    s0 += __shfl_down(s0, off);
    s1 += __shfl_down(s1, off);
    s2 += __shfl_down(s2, off);
  }
  __shared__ double red[4][3];
  int lane = t & 63, wv = t >> 6;
  if (lane == 0){ red[wv][0] = s0; red[wv][1] = s1; red[wv][2] = s2; }
  __syncthreads();
  if (t == 0){
    double So = red[0][0]+red[1][0]+red[2][0]+red[3][0];
    double Sx = red[0][1]+red[1][1]+red[2][1]+red[3][1];
    double Sox= red[0][2]+red[1][2]+red[2][2]+red[3][2];
    sc->c0 = (So - Sox) / ((double)NN - Sx + 1e-8);
    sc->c1 = Sox / (Sx + 1e-8);
  }
}

// final: recompute nx deterministically (same FP ops as sums_k), apply Chan-Vese
__global__ __launch_bounds__(256)
void final_k(const float* __restrict__ x, const float* __restrict__ orig,
             const Scal* __restrict__ sc, float* __restrict__ out){
  double thr = sc->thr, c0 = sc->c0, c1 = sc->c1;
  const int nItems = NN/4;
  const int lane = threadIdx.x & 63;
  for (int it = blockIdx.x*blockDim.x + threadIdx.x; it < nItems; it += gridDim.x*blockDim.x){
    int i = it >> 9;
    int q = it & 511;
    float a[6], b[6], c[6];
    growin(x, i-1, q, lane, a);
    growin(x, i,   q, lane, b);
    growin(x, i+1, q, lane, c);
    float4 og = *reinterpret_cast<const float4*>(orig + (size_t)i*WW + 4*q);
    float ov[4] = {og.x, og.y, og.z, og.w};
    float r[4];
    #pragma unroll
    for (int j = 0; j < 4; j++){
      float M9 = mx3(mx3(a[j],a[j+1],a[j+2]), mx3(b[j],b[j+1],b[j+2]), mx3(c[j],c[j+1],c[j+2]));
      float nx = ((double)ov[j] > thr) ? (1.0f + M9) : b[j+1];
      double o = (double)ov[j];
      double d1 = o - c1, d0 = o - c0;
      double cv = d1*d1 - d0*d0;
      r[j] = (cv < 0.0) ? 1.0f : ((cv > 0.0) ? 0.0f : nx);
    }
    *reinterpret_cast<float4*>(out + (size_t)i*WW + 4*q) = make_float4(r[0],r[1],r[2],r[3]);
  }
}

extern "C" void kernel_launch(void* const* d_in, const int* in_sizes, int n_in,
                              void* d_out, int out_size, void* d_ws, size_t ws_size,
                              hipStream_t stream) {
  const float* input  = (const float*)d_in[0];
  const float* origin = (const float*)d_in[1];
  float* out = (float*)d_out;

  char* ws = (char*)d_ws;
  float*    bufA   = (float*)ws;
  unsigned* coarse = (unsigned*)(ws + OFF_COARSE);
  unsigned* under  = (unsigned*)(ws + OFF_UNDER);
  unsigned* over   = (unsigned*)(ws + OFF_OVER);
  unsigned* midA   = (unsigned*)(ws + OFF_MIDA);
  unsigned* midB   = (unsigned*)(ws + OFF_MIDB);
  unsigned* h2A    = (unsigned*)(ws + OFF_H2A);
  unsigned* h2B    = (unsigned*)(ws + OFF_H2B);
  Scal*     scal   = (Scal*)(ws + OFF_SCAL);
  double*   part   = (double*)(ws + OFF_PART);

  hipMemsetAsync(ws + OFF_CTL, 0, CTL_BYTES, stream);

  // all 6 smoothing ops + coarse hist; x -> bufA (d_out written only by final_k)
  fused_morph_k<<<MORPH_BLOCKS, 256, 0, stream>>>(input, bufA, coarse, under, over);

  scan_coarse_k<<<1, 256, 0, stream>>>(coarse, under, scal);
  fine2d_k<<<2048, 256, 0, stream>>>(bufA, scal, midA, midB, h2A, h2B);
  scan_ml_k<<<1, 256, 0, stream>>>(midA, midB, h2A, h2B, scal);

  sums_k<<<NPART, 256, 0, stream>>>(bufA, origin, scal, part);
  c0c1_k<<<1, 256, 0, stream>>>(part, scal);
  final_k<<<2048, 256, 0, stream>>>(bufA, origin, scal, out);
}